// Round 3
// baseline (722.300 us; speedup 1.0000x reference)
//
#include <hip/hip_runtime.h>
#include <cstddef>

#define NS 256
#define NF 256
#define NC1 16
#define NC2 32

// ---------------------------------------------------------------------------
// prep: block 0 = 1-D bilinear profiles (transposed layout), block 1 = Weff
// (composed 5x5 adjoint kernel), block 2 = base init with proj_b.
__global__ __launch_bounds__(256) void k_prep(
    const int* __restrict__ obx, const int* __restrict__ oby,
    const int* __restrict__ obw, const int* __restrict__ obh,
    const int* __restrict__ ghp, const int* __restrict__ gwp,
    const float* __restrict__ w1, const float* __restrict__ w2,
    const float* __restrict__ pb,
    float* __restrict__ pyT, float* __restrict__ pxT,
    float* __restrict__ hy, float* __restrict__ hx,
    float* __restrict__ Weff, float* __restrict__ base) {
  int tid = threadIdx.x;
  if (blockIdx.x == 0) {
    int n = tid;
    float gh = (float)ghp[0], gw = (float)gwp[0];
    float sy = gh / 100.0f, sx = gw / 100.0f;
    int x0 = obx[n], y0 = oby[n], w = obw[n], h = obh[n];
    for (int j = 0; j < 100; ++j) {
      float u = (j + 0.5f) * sx - 0.5f;
      int a0 = (int)floorf(u);
      float t = u - (float)a0;
      float v0 = (a0 >= x0 && a0 < x0 + w) ? 1.f : 0.f;
      float v1 = (a0 + 1 >= x0 && a0 + 1 < x0 + w) ? 1.f : 0.f;
      pxT[j * 256 + n] = (1.f - t) * v0 + t * v1;
      u = (j + 0.5f) * sy - 0.5f;
      a0 = (int)floorf(u);
      t = u - (float)a0;
      v0 = (a0 >= y0 && a0 < y0 + h) ? 1.f : 0.f;
      v1 = (a0 + 1 >= y0 && a0 + 1 < y0 + h) ? 1.f : 0.f;
      pyT[j * 256 + n] = (1.f - t) * v0 + t * v1;
    }
    if (n < 100) {
      int j = n;
      float u = (j + 0.5f) * sx - 0.5f;
      int a0 = (int)floorf(u);
      float t = u - (float)a0;
      float v0 = (a0 >= 0 && a0 < 100) ? 1.f : 0.f;
      float v1 = (a0 + 1 >= 0 && a0 + 1 < 100) ? 1.f : 0.f;
      hx[j] = (1.f - t) * v0 + t * v1;
      u = (j + 0.5f) * sy - 0.5f;
      a0 = (int)floorf(u);
      t = u - (float)a0;
      v0 = (a0 >= 0 && a0 < 100) ? 1.f : 0.f;
      v1 = (a0 + 1 >= 0 && a0 + 1 < 100) ? 1.f : 0.f;
      hy[j] = (1.f - t) * v0 + t * v1;
    }
  } else if (blockIdx.x == 1) {
    for (int idx = tid; idx < NC2 * 25; idx += 256) {
      int c2 = idx / 25, d = idx % 25;
      int dy = d / 5, dx = d % 5;
      float s = 0.f;
      for (int c1 = 0; c1 < NC1; ++c1)
        for (int sy = 0; sy < 3; ++sy) {
          int ty = dy - sy;
          if (ty < 0 || ty > 2) continue;
          for (int sx = 0; sx < 3; ++sx) {
            int tx = dx - sx;
            if (tx < 0 || tx > 2) continue;
            s += w1[((c1 * 2 + 1) * 3 + (2 - sy)) * 3 + (2 - sx)] *
                 w2[((c2 * NC1 + c1) * 9 + (2 - ty) * 3 + (2 - tx))];
          }
        }
      Weff[idx] = s;
    }
  } else {
    base[tid] = pb[tid];
  }
}

// ---------------------------------------------------------------------------
// Fused human-channel conv1+conv2: t1 is built ANALYTICALLY from hy/hx into
// LDS (9 FMA/elem, no global t1 traffic), then 3x3x16 conv -> t2h.
// grid (100 rows, 4 c2-groups).
__global__ __launch_bounds__(256) void k_t2h(
    const float* __restrict__ w1, const float* __restrict__ b1,
    const float* __restrict__ w2, const float* __restrict__ b2,
    const float* __restrict__ hy, const float* __restrict__ hx,
    float* __restrict__ t2h) {
  __shared__ float t1s[NC1 * 3 * 104];  // [c1][r(3)][slot j: data col j-1]
  __shared__ float hxs[104];            // slot j: data col j-2
  __shared__ float hys[8];              // slot d: data row row0-2+d
  int tid = threadIdx.x;
  int row0 = blockIdx.x;
  int c2 = blockIdx.y * 8 + (tid >> 5);
  int colg = tid & 31;

  if (tid < 104) {
    int c = tid - 2;
    hxs[tid] = (c >= 0 && c < 100) ? hx[c] : 0.f;
  }
  if (tid >= 104 && tid < 109) {
    int d = tid - 104;
    int r = row0 - 2 + d;
    hys[d] = (r >= 0 && r < 100) ? hy[r] : 0.f;
  }
  __syncthreads();
  for (int i = tid; i < NC1 * 3 * 104; i += 256) {
    int c1 = i / 312, rem = i - c1 * 312;
    int r = rem / 104, j = rem - r * 104;
    int yy = row0 + r - 1, jc = j - 1;
    float val = 0.f;
    if (yy >= 0 && yy < 100 && jc >= 0 && jc < 100) {
      val = b1[c1];
#pragma unroll
      for (int dy = 0; dy < 3; ++dy) {
        float hv = hys[r + dy];
#pragma unroll
        for (int dx = 0; dx < 3; ++dx)
          val += w1[((c1 * 2 + 0) * 3 + dy) * 3 + dx] * hv * hxs[j + dx];
      }
    }
    t1s[i] = val;
  }
  __syncthreads();
  if (colg < 25) {
    float acc[4];
    float bb = b2[c2];
#pragma unroll
    for (int cc = 0; cc < 4; ++cc) acc[cc] = bb;
    for (int c1 = 0; c1 < NC1; ++c1)
#pragma unroll
      for (int r = 0; r < 3; ++r) {
        const float* tp = &t1s[(c1 * 3 + r) * 104 + colg * 4];
        float t0 = tp[0], t1 = tp[1], t2 = tp[2], t3 = tp[3], t4 = tp[4],
              t5 = tp[5];
#pragma unroll
        for (int dx = 0; dx < 3; ++dx) {
          float wv = w2[(c2 * NC1 + c1) * 9 + r * 3 + dx];
          float tv[6] = {t0, t1, t2, t3, t4, t5};
#pragma unroll
          for (int cc = 0; cc < 4; ++cc) acc[cc] += wv * tv[cc + dx];
        }
      }
    *(float4*)&t2h[c2 * 10000 + row0 * 100 + colg * 4] =
        make_float4(acc[0], acc[1], acc[2], acc[3]);
  }
}

// ---------------------------------------------------------------------------
// Composed 5x5 adjoint over proj rows. 24-row tiles, R3C4, 32-lane row
// groups, stride 112 (28 f4). grid (5 row-tiles, 256 f) = 1280 blocks ->
// 5 blocks/CU, 20 waves/CU. LDS 2x28x112 = 25 KB (cap 6 blocks).
// t2h base-dot rides the staging loads (no mid-loop global latency).
__global__ __launch_bounds__(256, 5) void k_adj5(
    const float* __restrict__ P, const float* __restrict__ Weff,
    const float* __restrict__ t2h, float* __restrict__ G,
    float* __restrict__ base, float* __restrict__ rimbuf) {
  __shared__ __align__(16) float buf[2][28 * 112];
  int tid = threadIdx.x;
  int f = blockIdx.y;
  int r0 = blockIdx.x * 24;  // tiles: 0,24,48,72,96 (last = 4 rows)
  const float* Pf = P + (size_t)f * (NC2 * 10000);
  float* rimf = rimbuf + (size_t)f * (NC2 * 400);
  float bacc = 0.f;

  auto stage = [&](float* b, int c2) {
    const float* Pc = Pf + c2 * 10000;
    const float* Tc = t2h + c2 * 10000;
    float* rimc = rimf + c2 * 400;
    for (int w = tid; w < 28 * 32; w += 256) {
      int row = w >> 5, k = w & 31;
      int gr = r0 - 2 + row;
      if (k < 25 && gr >= 0 && gr < 100) {
        float4 val = *(const float4*)(Pc + gr * 100 + k * 4);
        *(float4*)(b + row * 112 + 4 + k * 4) = val;
        if (gr >= r0 && gr < r0 + 24) {  // owned rows: base-dot here
          float4 t = *(const float4*)(Tc + gr * 100 + k * 4);
          bacc += t.x * val.x + t.y * val.y + t.z * val.z + t.w * val.w;
        }
        if (gr == 0) *(float4*)(rimc + k * 4) = val;
        if (gr == 99) *(float4*)(rimc + 100 + k * 4) = val;
        if (k == 0) rimc[200 + gr] = val.x;
        if (k == 24) rimc[300 + gr] = val.w;
      }
    }
  };

  for (int i = tid; i < 2 * 28 * 112; i += 256) ((float*)buf)[i] = 0.f;
  __syncthreads();
  stage(buf[0], 0);

  int colg = tid & 31, rowg = tid >> 5;
  bool act = (colg < 25);
  float acc[3][4] = {};

  for (int c2 = 0; c2 < NC2; ++c2) {
    __syncthreads();
    if (c2 + 1 < NC2) stage(buf[(c2 + 1) & 1], c2 + 1);
    if (act) {
      const float* lp = &buf[c2 & 1][(rowg * 3) * 112 + colg * 4];
      const float* We = Weff + c2 * 25;
#pragma unroll
      for (int ir = 0; ir < 7; ++ir) {
        float4 A = *(const float4*)(lp + ir * 112);
        float4 Bv = *(const float4*)(lp + ir * 112 + 4);
        float4 Cv = *(const float4*)(lp + ir * 112 + 8);
        float v[12] = {A.x,  A.y,  A.z,  A.w,  Bv.x, Bv.y,
                       Bv.z, Bv.w, Cv.x, Cv.y, Cv.z, Cv.w};
#pragma unroll
        for (int rr = 0; rr < 3; ++rr) {
          int dy = ir - rr;
          if (dy < 0 || dy > 4) continue;
#pragma unroll
          for (int dx = 0; dx < 5; ++dx) {
            float w = We[dy * 5 + dx];
#pragma unroll
            for (int cc = 0; cc < 4; ++cc) acc[rr][cc] += w * v[2 + dx + cc];
          }
        }
      }
    }
  }
  if (act) {
#pragma unroll
    for (int rr = 0; rr < 3; ++rr) {
      int grow = r0 + rowg * 3 + rr;
      if (grow < 100)
        *(float4*)&G[(size_t)f * 10000 + grow * 100 + colg * 4] =
            *(float4*)&acc[rr][0];
    }
  }
  __syncthreads();
  float* red = &buf[0][0];
  red[tid] = bacc;
  __syncthreads();
  for (int s = 128; s > 0; s >>= 1) {
    if (tid < s) red[tid] += red[tid + s];
    __syncthreads();
  }
  if (tid == 0) atomicAdd(&base[f], red[0]);
}

// ---------------------------------------------------------------------------
// Fused rim correction: all 32 c2 in one block per f. grid (256 f).
__global__ __launch_bounds__(256) void k_rim(
    const float* __restrict__ rimbuf, const float* __restrict__ w2,
    const float* __restrict__ w1, float* __restrict__ G) {
  __shared__ float rs[NC2 * 400];   // 51.2 KB
  __shared__ float hs[NC1 * 404];   // 25.9 KB
  __shared__ float w1s[288];
  int tid = threadIdx.x;
  int f = blockIdx.x;
  for (int i = tid; i < NC2 * 400; i += 256)
    rs[i] = rimbuf[(size_t)f * (NC2 * 400) + i];
  for (int i = tid; i < 288; i += 256) w1s[i] = w1[i];
  __syncthreads();
  for (int qq = 0; qq < 2; ++qq) {
    int j = tid + qq * 256;
    if (j >= 404) break;
    int qy, qx;
    if (j < 102) { qy = -1; qx = j - 1; }
    else if (j < 204) { qy = 100; qx = j - 103; }
    else if (j < 304) { qy = j - 204; qx = -1; }
    else { qy = j - 304; qx = 100; }
    float hacc[NC1];
#pragma unroll
    for (int c1 = 0; c1 < NC1; ++c1) hacc[c1] = 0.f;
#pragma unroll
    for (int ty = 0; ty < 3; ++ty)
#pragma unroll
      for (int tx = 0; tx < 3; ++tx) {
        int r = qy + ty - 1, c = qx + tx - 1;
        bool ok = (r >= 0 && r < 100 && c >= 0 && c < 100);
        int side, i2;
        if (r == 0) { side = 0; i2 = c; }
        else if (r == 99) { side = 1; i2 = c; }
        else if (c == 0) { side = 2; i2 = r; }
        else { side = 3; i2 = r; }
        i2 = min(max(i2, 0), 99);
        int rbase = side * 100 + i2;
        if (ok) {
          for (int c2 = 0; c2 < NC2; ++c2) {
            float val = rs[c2 * 400 + rbase];
#pragma unroll
            for (int c1 = 0; c1 < NC1; ++c1)
              hacc[c1] +=
                  w2[(c2 * NC1 + c1) * 9 + (2 - ty) * 3 + (2 - tx)] * val;
          }
        }
      }
#pragma unroll
    for (int c1 = 0; c1 < NC1; ++c1) hs[c1 * 404 + j] = hacc[c1];
  }
  __syncthreads();
  for (int idx = tid; idx < 396; idx += 256) {
    int py, px;
    if (idx < 100) { py = 0; px = idx; }
    else if (idx < 200) { py = 99; px = idx - 100; }
    else if (idx < 298) { py = idx - 199; px = 0; }
    else { py = idx - 297; px = 99; }
    float corr = 0.f;
    for (int sy = 0; sy < 3; ++sy)
      for (int sx = 0; sx < 3; ++sx) {
        int qy = py + sy - 1, qx = px + sx - 1;
        bool ph = (qy == -1 || qy == 100 || qx == -1 || qx == 100);
        if (!ph) continue;
        int j;
        if (qy == -1) j = qx + 1;
        else if (qy == 100) j = 103 + qx;
        else if (qx == -1) j = 204 + qy;
        else j = 304 + qy;
#pragma unroll
        for (int c1 = 0; c1 < NC1; ++c1)
          corr += w1s[((c1 * 2 + 1) * 3 + (2 - sy)) * 3 + (2 - sx)] *
                  hs[c1 * 404 + j];
      }
    G[(size_t)f * 10000 + py * 100 + px] -= corr;
  }
}

// ---------------------------------------------------------------------------
// GEMM: part[kS][nT][fT][128n][128f] = sum over 80 k of M[k,n]*G[f,k].
// grid (2 fT, 2 nT, 125 kS). Thread's f-columns: split pair {tf*4, 64+tf*4}.
__global__ __launch_bounds__(256) void k_gemm(
    const float* __restrict__ G, const float* __restrict__ pyT,
    const float* __restrict__ pxT, float* __restrict__ part) {
  __shared__ float Gs[8 * 132];
  __shared__ float Ms[8 * 128];
  int tid = threadIdx.x;
  int fT = blockIdx.x, nT = blockIdx.y, kS = blockIdx.z;
  int f0 = fT * 128, n0 = nT * 128, kb0 = kS * 80;
  int tf = tid % 16, tn = tid / 16;
  int fG = tid >> 1, kq = (tid & 1) * 4;
  int nl = tid & 127, kh = tid >> 7;
  float acc[8][8] = {};
  for (int ch = 0; ch < 10; ++ch) {
    int kb = kb0 + ch * 8;
    __syncthreads();
    {
      float4 g = *(const float4*)&G[(size_t)(f0 + fG) * 10000 + kb + kq];
      Gs[(kq + 0) * 132 + fG] = g.x;
      Gs[(kq + 1) * 132 + fG] = g.y;
      Gs[(kq + 2) * 132 + fG] = g.z;
      Gs[(kq + 3) * 132 + fG] = g.w;
    }
#pragma unroll
    for (int kk = 0; kk < 4; ++kk) {
      int k = kh * 4 + kk;
      int p = kb + k;
      int pi = p / 100, pj = p - pi * 100;
      Ms[k * 128 + nl] = pyT[pi * 256 + n0 + nl] * pxT[pj * 256 + n0 + nl];
    }
    __syncthreads();
#pragma unroll
    for (int k = 0; k < 8; ++k) {
      float4 ga = *(const float4*)&Gs[k * 132 + tf * 4];
      float4 gb = *(const float4*)&Gs[k * 132 + 64 + tf * 4];
      float4 ma = *(const float4*)&Ms[k * 128 + tn * 8];
      float4 mb = *(const float4*)&Ms[k * 128 + tn * 8 + 4];
      float gv[8] = {ga.x, ga.y, ga.z, ga.w, gb.x, gb.y, gb.z, gb.w};
      float mv[8] = {ma.x, ma.y, ma.z, ma.w, mb.x, mb.y, mb.z, mb.w};
#pragma unroll
      for (int nn = 0; nn < 8; ++nn)
#pragma unroll
        for (int ff = 0; ff < 8; ++ff) acc[nn][ff] += mv[nn] * gv[ff];
    }
  }
  size_t pb = (((size_t)kS * 2 + nT) * 2 + fT) * 16384;
#pragma unroll
  for (int nn = 0; nn < 8; ++nn) {
    int row = tn * 8 + nn;
    *(float4*)&part[pb + row * 128 + tf * 4] =
        make_float4(acc[nn][0], acc[nn][1], acc[nn][2], acc[nn][3]);
    *(float4*)&part[pb + row * 128 + 64 + tf * 4] =
        make_float4(acc[nn][4], acc[nn][5], acc[nn][6], acc[nn][7]);
  }
}

// Reduce split-K partials + base into out[n,f].
__global__ __launch_bounds__(256) void k_out(
    const float* __restrict__ part, const float* __restrict__ base,
    float* __restrict__ out) {
  int gid = blockIdx.x * 256 + threadIdx.x;
  int f = gid & 255, n = gid >> 8;
  int nT = n >> 7, nl = n & 127, fT = f >> 7, fl = f & 127;
  float val = base[f];
  size_t off = ((size_t)(nT * 2 + fT)) * 16384 + nl * 128 + fl;
  for (int s = 0; s < 125; ++s) val += part[(size_t)s * 65536 + off];
  out[(size_t)n * 256 + f] = val;
}

// ---------------------------------------------------------------------------
extern "C" void kernel_launch(void* const* d_in, const int* in_sizes, int n_in,
                              void* d_out, int out_size, void* d_ws,
                              size_t ws_size, hipStream_t stream) {
  const int* obj_x = (const int*)d_in[0];
  const int* obj_y = (const int*)d_in[1];
  const int* obj_w = (const int*)d_in[2];
  const int* obj_h = (const int*)d_in[3];
  const int* g_h = (const int*)d_in[4];
  const int* g_w = (const int*)d_in[5];
  const float* conv1_w = (const float*)d_in[6];
  const float* conv1_b = (const float*)d_in[7];
  const float* conv2_w = (const float*)d_in[8];
  const float* conv2_b = (const float*)d_in[9];
  const float* proj_w = (const float*)d_in[10];
  const float* proj_b = (const float*)d_in[11];
  float* out = (float*)d_out;

  float* w = (float*)d_ws;
  float* pyT = w;    w += 100 * 256;
  float* pxT = w;    w += 100 * 256;
  float* hy = w;     w += 100;
  float* hx = w;     w += 100;
  float* t2h = w;    w += NC2 * 10000;
  float* base = w;   w += NF;
  float* Weff = w;   w += NC2 * 25;
  float* G = w;      w += (size_t)NF * 10000;
  float* rimbuf = w; w += (size_t)NF * NC2 * 400;
  float* part = w;   w += (size_t)500 * 16384;  // total ~58 MB

  k_prep<<<3, 256, 0, stream>>>(obj_x, obj_y, obj_w, obj_h, g_h, g_w, conv1_w,
                                conv2_w, proj_b, pyT, pxT, hy, hx, Weff, base);
  k_t2h<<<dim3(100, 4), 256, 0, stream>>>(conv1_w, conv1_b, conv2_w, conv2_b,
                                          hy, hx, t2h);
  k_adj5<<<dim3(5, 256), 256, 0, stream>>>(proj_w, Weff, t2h, G, base, rimbuf);
  k_rim<<<256, 256, 0, stream>>>(rimbuf, conv2_w, conv1_w, G);
  k_gemm<<<dim3(2, 2, 125), 256, 0, stream>>>(G, pyT, pxT, part);
  k_out<<<256, 256, 0, stream>>>(part, base, out);
}

// Round 4
// 682.659 us; speedup vs baseline: 1.0581x; 1.0581x over previous
//
#include <hip/hip_runtime.h>
#include <cstddef>

#define NS 256
#define NF 256
#define NC1 16
#define NC2 32

// ---------------------------------------------------------------------------
// prep: block 0 = 1-D bilinear profiles (transposed layout), block 1 = Weff
// (composed 5x5 adjoint kernel), block 2 = base init with proj_b.
__global__ __launch_bounds__(256) void k_prep(
    const int* __restrict__ obx, const int* __restrict__ oby,
    const int* __restrict__ obw, const int* __restrict__ obh,
    const int* __restrict__ ghp, const int* __restrict__ gwp,
    const float* __restrict__ w1, const float* __restrict__ w2,
    const float* __restrict__ pb,
    float* __restrict__ pyT, float* __restrict__ pxT,
    float* __restrict__ hy, float* __restrict__ hx,
    float* __restrict__ Weff, float* __restrict__ base) {
  int tid = threadIdx.x;
  if (blockIdx.x == 0) {
    int n = tid;
    float gh = (float)ghp[0], gw = (float)gwp[0];
    float sy = gh / 100.0f, sx = gw / 100.0f;
    int x0 = obx[n], y0 = oby[n], w = obw[n], h = obh[n];
    for (int j = 0; j < 100; ++j) {
      float u = (j + 0.5f) * sx - 0.5f;
      int a0 = (int)floorf(u);
      float t = u - (float)a0;
      float v0 = (a0 >= x0 && a0 < x0 + w) ? 1.f : 0.f;
      float v1 = (a0 + 1 >= x0 && a0 + 1 < x0 + w) ? 1.f : 0.f;
      pxT[j * 256 + n] = (1.f - t) * v0 + t * v1;
      u = (j + 0.5f) * sy - 0.5f;
      a0 = (int)floorf(u);
      t = u - (float)a0;
      v0 = (a0 >= y0 && a0 < y0 + h) ? 1.f : 0.f;
      v1 = (a0 + 1 >= y0 && a0 + 1 < y0 + h) ? 1.f : 0.f;
      pyT[j * 256 + n] = (1.f - t) * v0 + t * v1;
    }
    if (n < 100) {
      int j = n;
      float u = (j + 0.5f) * sx - 0.5f;
      int a0 = (int)floorf(u);
      float t = u - (float)a0;
      float v0 = (a0 >= 0 && a0 < 100) ? 1.f : 0.f;
      float v1 = (a0 + 1 >= 0 && a0 + 1 < 100) ? 1.f : 0.f;
      hx[j] = (1.f - t) * v0 + t * v1;
      u = (j + 0.5f) * sy - 0.5f;
      a0 = (int)floorf(u);
      t = u - (float)a0;
      v0 = (a0 >= 0 && a0 < 100) ? 1.f : 0.f;
      v1 = (a0 + 1 >= 0 && a0 + 1 < 100) ? 1.f : 0.f;
      hy[j] = (1.f - t) * v0 + t * v1;
    }
  } else if (blockIdx.x == 1) {
    for (int idx = tid; idx < NC2 * 25; idx += 256) {
      int c2 = idx / 25, d = idx % 25;
      int dy = d / 5, dx = d % 5;
      float s = 0.f;
      for (int c1 = 0; c1 < NC1; ++c1)
        for (int sy = 0; sy < 3; ++sy) {
          int ty = dy - sy;
          if (ty < 0 || ty > 2) continue;
          for (int sx = 0; sx < 3; ++sx) {
            int tx = dx - sx;
            if (tx < 0 || tx > 2) continue;
            s += w1[((c1 * 2 + 1) * 3 + (2 - sy)) * 3 + (2 - sx)] *
                 w2[((c2 * NC1 + c1) * 9 + (2 - ty) * 3 + (2 - tx))];
          }
        }
      Weff[idx] = s;
    }
  } else {
    base[tid] = pb[tid];
  }
}

// ---------------------------------------------------------------------------
// Fused human-channel conv1+conv2: t1 built analytically from hy/hx in LDS.
// grid (100 rows, 4 c2-groups).
__global__ __launch_bounds__(256) void k_t2h(
    const float* __restrict__ w1, const float* __restrict__ b1,
    const float* __restrict__ w2, const float* __restrict__ b2,
    const float* __restrict__ hy, const float* __restrict__ hx,
    float* __restrict__ t2h) {
  __shared__ float t1s[NC1 * 3 * 104];
  __shared__ float hxs[104];
  __shared__ float hys[8];
  int tid = threadIdx.x;
  int row0 = blockIdx.x;
  int c2 = blockIdx.y * 8 + (tid >> 5);
  int colg = tid & 31;

  if (tid < 104) {
    int c = tid - 2;
    hxs[tid] = (c >= 0 && c < 100) ? hx[c] : 0.f;
  }
  if (tid >= 104 && tid < 109) {
    int d = tid - 104;
    int r = row0 - 2 + d;
    hys[d] = (r >= 0 && r < 100) ? hy[r] : 0.f;
  }
  __syncthreads();
  for (int i = tid; i < NC1 * 3 * 104; i += 256) {
    int c1 = i / 312, rem = i - c1 * 312;
    int r = rem / 104, j = rem - r * 104;
    int yy = row0 + r - 1, jc = j - 1;
    float val = 0.f;
    if (yy >= 0 && yy < 100 && jc >= 0 && jc < 100) {
      val = b1[c1];
#pragma unroll
      for (int dy = 0; dy < 3; ++dy) {
        float hv = hys[r + dy];
#pragma unroll
        for (int dx = 0; dx < 3; ++dx)
          val += w1[((c1 * 2 + 0) * 3 + dy) * 3 + dx] * hv * hxs[j + dx];
      }
    }
    t1s[i] = val;
  }
  __syncthreads();
  if (colg < 25) {
    float acc[4];
    float bb = b2[c2];
#pragma unroll
    for (int cc = 0; cc < 4; ++cc) acc[cc] = bb;
    for (int c1 = 0; c1 < NC1; ++c1)
#pragma unroll
      for (int r = 0; r < 3; ++r) {
        const float* tp = &t1s[(c1 * 3 + r) * 104 + colg * 4];
        float t0 = tp[0], t1 = tp[1], t2 = tp[2], t3 = tp[3], t4 = tp[4],
              t5 = tp[5];
#pragma unroll
        for (int dx = 0; dx < 3; ++dx) {
          float wv = w2[(c2 * NC1 + c1) * 9 + r * 3 + dx];
          float tv[6] = {t0, t1, t2, t3, t4, t5};
#pragma unroll
          for (int cc = 0; cc < 4; ++cc) acc[cc] += wv * tv[cc + dx];
        }
      }
    *(float4*)&t2h[c2 * 10000 + row0 * 100 + colg * 4] =
        make_float4(acc[0], acc[1], acc[2], acc[3]);
  }
}

// ---------------------------------------------------------------------------
// Composed 5x5 adjoint, GLOBAL-DIRECT (no LDS staging of P).
// Each thread: R5C4 register window win[9][3] (float4), reads P via L1/L2
// (block working set ~23 KB/c2 fits L1). No barriers in the c2 loop.
// grid (2 row-halves, 256 f). rowg = tid/25 (0..9, 5 rows), colg = tid%25.
// Weff in LDS (broadcast reads). t2h dot + rim extraction ride the window.
__global__ __launch_bounds__(256, 2) void k_adj5(
    const float* __restrict__ P, const float* __restrict__ Weff,
    const float* __restrict__ t2h, float* __restrict__ G,
    float* __restrict__ base, float* __restrict__ rimbuf) {
  __shared__ float WeS[NC2 * 25];
  __shared__ float red[256];
  int tid = threadIdx.x;
  int f = blockIdx.y;
  int r0 = blockIdx.x * 50;
  const float* Pf = P + (size_t)f * (NC2 * 10000);
  float* rimf = rimbuf + (size_t)f * (NC2 * 400);

  for (int i = tid; i < NC2 * 25; i += 256) WeS[i] = Weff[i];
  __syncthreads();

  int rowg = tid / 25, colg = tid - rowg * 25;
  bool act = tid < 250;
  int rs = r0 + rowg * 5;  // first owned row
  float acc[5][4] = {};
  float bacc = 0.f;

  if (act) {
    for (int c2 = 0; c2 < NC2; ++c2) {
      const float* Pc = Pf + c2 * 10000;
      const float* Tc = t2h + c2 * 10000;
      float* rimc = rimf + c2 * 400;
      // register window: rows rs-2..rs+6, col f4s colg-1..colg+1
      float4 win[9][3];
#pragma unroll
      for (int ir = 0; ir < 9; ++ir) {
        int gr = rs - 2 + ir;
        bool rok = (gr >= 0 && gr < 100);
#pragma unroll
        for (int j = 0; j < 3; ++j) {
          int cf = colg - 1 + j;
          win[ir][j] = (rok && cf >= 0 && cf < 25)
                           ? *(const float4*)(Pc + gr * 100 + cf * 4)
                           : make_float4(0.f, 0.f, 0.f, 0.f);
        }
      }
      // Weff to registers (LDS broadcast)
      float Wv[25];
#pragma unroll
      for (int i = 0; i < 25; ++i) Wv[i] = WeS[c2 * 25 + i];
      // conv accumulate
#pragma unroll
      for (int ir = 0; ir < 9; ++ir) {
        float v[12] = {win[ir][0].x, win[ir][0].y, win[ir][0].z, win[ir][0].w,
                       win[ir][1].x, win[ir][1].y, win[ir][1].z, win[ir][1].w,
                       win[ir][2].x, win[ir][2].y, win[ir][2].z, win[ir][2].w};
#pragma unroll
        for (int rr = 0; rr < 5; ++rr) {
          int dy = ir - rr;
          if (dy < 0 || dy > 4) continue;
#pragma unroll
          for (int dx = 0; dx < 5; ++dx) {
            float w = Wv[dy * 5 + dx];
#pragma unroll
            for (int cc = 0; cc < 4; ++cc) acc[rr][cc] += w * v[2 + dx + cc];
          }
        }
      }
      // t2h base-dot over owned pixels (center f4 = win[rr+2][1])
#pragma unroll
      for (int rr = 0; rr < 5; ++rr) {
        float4 t = *(const float4*)(Tc + (rs + rr) * 100 + colg * 4);
        float4 p = win[rr + 2][1];
        bacc += t.x * p.x + t.y * p.y + t.z * p.z + t.w * p.w;
      }
      // rim extraction from registers
      if (rs == 0) *(float4*)(rimc + colg * 4) = win[2][1];
      if (rs == 95) *(float4*)(rimc + 100 + colg * 4) = win[6][1];
      if (colg == 0) {
#pragma unroll
        for (int rr = 0; rr < 5; ++rr) rimc[200 + rs + rr] = win[rr + 2][1].x;
      }
      if (colg == 24) {
#pragma unroll
        for (int rr = 0; rr < 5; ++rr) rimc[300 + rs + rr] = win[rr + 2][1].w;
      }
    }
#pragma unroll
    for (int rr = 0; rr < 5; ++rr)
      *(float4*)&G[(size_t)f * 10000 + (rs + rr) * 100 + colg * 4] =
          make_float4(acc[rr][0], acc[rr][1], acc[rr][2], acc[rr][3]);
  }
  red[tid] = bacc;
  __syncthreads();
  for (int s = 128; s > 0; s >>= 1) {
    if (tid < s) red[tid] += red[tid + s];
    __syncthreads();
  }
  if (tid == 0) atomicAdd(&base[f], red[0]);
}

// ---------------------------------------------------------------------------
// Fused rim correction: all 32 c2 in one block per f. grid (256 f).
__global__ __launch_bounds__(256) void k_rim(
    const float* __restrict__ rimbuf, const float* __restrict__ w2,
    const float* __restrict__ w1, float* __restrict__ G) {
  __shared__ float rs[NC2 * 400];
  __shared__ float hs[NC1 * 404];
  __shared__ float w1s[288];
  int tid = threadIdx.x;
  int f = blockIdx.x;
  for (int i = tid; i < NC2 * 400; i += 256)
    rs[i] = rimbuf[(size_t)f * (NC2 * 400) + i];
  for (int i = tid; i < 288; i += 256) w1s[i] = w1[i];
  __syncthreads();
  for (int qq = 0; qq < 2; ++qq) {
    int j = tid + qq * 256;
    if (j >= 404) break;
    int qy, qx;
    if (j < 102) { qy = -1; qx = j - 1; }
    else if (j < 204) { qy = 100; qx = j - 103; }
    else if (j < 304) { qy = j - 204; qx = -1; }
    else { qy = j - 304; qx = 100; }
    float hacc[NC1];
#pragma unroll
    for (int c1 = 0; c1 < NC1; ++c1) hacc[c1] = 0.f;
#pragma unroll
    for (int ty = 0; ty < 3; ++ty)
#pragma unroll
      for (int tx = 0; tx < 3; ++tx) {
        int r = qy + ty - 1, c = qx + tx - 1;
        bool ok = (r >= 0 && r < 100 && c >= 0 && c < 100);
        int side, i2;
        if (r == 0) { side = 0; i2 = c; }
        else if (r == 99) { side = 1; i2 = c; }
        else if (c == 0) { side = 2; i2 = r; }
        else { side = 3; i2 = r; }
        i2 = min(max(i2, 0), 99);
        int rbase = side * 100 + i2;
        if (ok) {
          for (int c2 = 0; c2 < NC2; ++c2) {
            float val = rs[c2 * 400 + rbase];
#pragma unroll
            for (int c1 = 0; c1 < NC1; ++c1)
              hacc[c1] +=
                  w2[(c2 * NC1 + c1) * 9 + (2 - ty) * 3 + (2 - tx)] * val;
          }
        }
      }
#pragma unroll
    for (int c1 = 0; c1 < NC1; ++c1) hs[c1 * 404 + j] = hacc[c1];
  }
  __syncthreads();
  for (int idx = tid; idx < 396; idx += 256) {
    int py, px;
    if (idx < 100) { py = 0; px = idx; }
    else if (idx < 200) { py = 99; px = idx - 100; }
    else if (idx < 298) { py = idx - 199; px = 0; }
    else { py = idx - 297; px = 99; }
    float corr = 0.f;
    for (int sy = 0; sy < 3; ++sy)
      for (int sx = 0; sx < 3; ++sx) {
        int qy = py + sy - 1, qx = px + sx - 1;
        bool ph = (qy == -1 || qy == 100 || qx == -1 || qx == 100);
        if (!ph) continue;
        int j;
        if (qy == -1) j = qx + 1;
        else if (qy == 100) j = 103 + qx;
        else if (qx == -1) j = 204 + qy;
        else j = 304 + qy;
#pragma unroll
        for (int c1 = 0; c1 < NC1; ++c1)
          corr += w1s[((c1 * 2 + 1) * 3 + (2 - sy)) * 3 + (2 - sx)] *
                  hs[c1 * 404 + j];
      }
    G[(size_t)f * 10000 + py * 100 + px] -= corr;
  }
}

// ---------------------------------------------------------------------------
// GEMM: part[kS][nT][fT][128n][128f] = sum over 80 k of M[k,n]*G[f,k].
// grid (2 fT, 2 nT, 125 kS).
__global__ __launch_bounds__(256) void k_gemm(
    const float* __restrict__ G, const float* __restrict__ pyT,
    const float* __restrict__ pxT, float* __restrict__ part) {
  __shared__ float Gs[8 * 132];
  __shared__ float Ms[8 * 128];
  int tid = threadIdx.x;
  int fT = blockIdx.x, nT = blockIdx.y, kS = blockIdx.z;
  int f0 = fT * 128, n0 = nT * 128, kb0 = kS * 80;
  int tf = tid % 16, tn = tid / 16;
  int fG = tid >> 1, kq = (tid & 1) * 4;
  int nl = tid & 127, kh = tid >> 7;
  float acc[8][8] = {};
  for (int ch = 0; ch < 10; ++ch) {
    int kb = kb0 + ch * 8;
    __syncthreads();
    {
      float4 g = *(const float4*)&G[(size_t)(f0 + fG) * 10000 + kb + kq];
      Gs[(kq + 0) * 132 + fG] = g.x;
      Gs[(kq + 1) * 132 + fG] = g.y;
      Gs[(kq + 2) * 132 + fG] = g.z;
      Gs[(kq + 3) * 132 + fG] = g.w;
    }
#pragma unroll
    for (int kk = 0; kk < 4; ++kk) {
      int k = kh * 4 + kk;
      int p = kb + k;
      int pi = p / 100, pj = p - pi * 100;
      Ms[k * 128 + nl] = pyT[pi * 256 + n0 + nl] * pxT[pj * 256 + n0 + nl];
    }
    __syncthreads();
#pragma unroll
    for (int k = 0; k < 8; ++k) {
      float4 ga = *(const float4*)&Gs[k * 132 + tf * 4];
      float4 gb = *(const float4*)&Gs[k * 132 + 64 + tf * 4];
      float4 ma = *(const float4*)&Ms[k * 128 + tn * 8];
      float4 mb = *(const float4*)&Ms[k * 128 + tn * 8 + 4];
      float gv[8] = {ga.x, ga.y, ga.z, ga.w, gb.x, gb.y, gb.z, gb.w};
      float mv[8] = {ma.x, ma.y, ma.z, ma.w, mb.x, mb.y, mb.z, mb.w};
#pragma unroll
      for (int nn = 0; nn < 8; ++nn)
#pragma unroll
        for (int ff = 0; ff < 8; ++ff) acc[nn][ff] += mv[nn] * gv[ff];
    }
  }
  size_t pb = (((size_t)kS * 2 + nT) * 2 + fT) * 16384;
#pragma unroll
  for (int nn = 0; nn < 8; ++nn) {
    int row = tn * 8 + nn;
    *(float4*)&part[pb + row * 128 + tf * 4] =
        make_float4(acc[nn][0], acc[nn][1], acc[nn][2], acc[nn][3]);
    *(float4*)&part[pb + row * 128 + 64 + tf * 4] =
        make_float4(acc[nn][4], acc[nn][5], acc[nn][6], acc[nn][7]);
  }
}

// Reduce stage 1: sum 25 slices per group. grid (256, 5).
__global__ __launch_bounds__(256) void k_out1(
    const float* __restrict__ part, float* __restrict__ part2) {
  int gid = blockIdx.x * 256 + threadIdx.x;
  int g = blockIdx.y;
  int f = gid & 255, n = gid >> 8;
  int nT = n >> 7, nl = n & 127, fT = f >> 7, fl = f & 127;
  size_t off = ((size_t)(nT * 2 + fT)) * 16384 + nl * 128 + fl;
  float val = 0.f;
  for (int s = g * 25; s < g * 25 + 25; ++s)
    val += part[(size_t)s * 65536 + off];
  part2[(size_t)g * 65536 + gid] = val;
}

// Reduce stage 2: sum 5 groups + base. grid (256).
__global__ __launch_bounds__(256) void k_out2(
    const float* __restrict__ part2, const float* __restrict__ base,
    float* __restrict__ out) {
  int gid = blockIdx.x * 256 + threadIdx.x;
  int f = gid & 255;
  float val = base[f];
#pragma unroll
  for (int g = 0; g < 5; ++g) val += part2[(size_t)g * 65536 + gid];
  out[gid] = val;
}

// ---------------------------------------------------------------------------
extern "C" void kernel_launch(void* const* d_in, const int* in_sizes, int n_in,
                              void* d_out, int out_size, void* d_ws,
                              size_t ws_size, hipStream_t stream) {
  const int* obj_x = (const int*)d_in[0];
  const int* obj_y = (const int*)d_in[1];
  const int* obj_w = (const int*)d_in[2];
  const int* obj_h = (const int*)d_in[3];
  const int* g_h = (const int*)d_in[4];
  const int* g_w = (const int*)d_in[5];
  const float* conv1_w = (const float*)d_in[6];
  const float* conv1_b = (const float*)d_in[7];
  const float* conv2_w = (const float*)d_in[8];
  const float* conv2_b = (const float*)d_in[9];
  const float* proj_w = (const float*)d_in[10];
  const float* proj_b = (const float*)d_in[11];
  float* out = (float*)d_out;

  float* w = (float*)d_ws;
  float* pyT = w;    w += 100 * 256;
  float* pxT = w;    w += 100 * 256;
  float* hy = w;     w += 100;
  float* hx = w;     w += 100;
  float* t2h = w;    w += NC2 * 10000;
  float* base = w;   w += NF;
  float* Weff = w;   w += NC2 * 25;
  float* G = w;      w += (size_t)NF * 10000;
  float* rimbuf = w; w += (size_t)NF * NC2 * 400;
  float* part = w;   w += (size_t)500 * 16384;
  float* part2 = w;  w += (size_t)5 * 65536;  // total ~60 MB

  k_prep<<<3, 256, 0, stream>>>(obj_x, obj_y, obj_w, obj_h, g_h, g_w, conv1_w,
                                conv2_w, proj_b, pyT, pxT, hy, hx, Weff, base);
  k_t2h<<<dim3(100, 4), 256, 0, stream>>>(conv1_w, conv1_b, conv2_w, conv2_b,
                                          hy, hx, t2h);
  k_adj5<<<dim3(2, 256), 256, 0, stream>>>(proj_w, Weff, t2h, G, base, rimbuf);
  k_rim<<<256, 256, 0, stream>>>(rimbuf, conv2_w, conv1_w, G);
  k_gemm<<<dim3(2, 2, 125), 256, 0, stream>>>(G, pyT, pxT, part);
  k_out1<<<dim3(256, 5), 256, 0, stream>>>(part, part2);
  k_out2<<<256, 256, 0, stream>>>(part2, base, out);
}